// Round 1
// baseline (129.472 us; speedup 1.0000x reference)
//
#include <hip/hip_runtime.h>

#define DM 512
#define DI 1024
#define MM 16

typedef __attribute__((ext_vector_type(4))) float f32x4;
typedef __attribute__((ext_vector_type(8))) short short8;
typedef __attribute__((ext_vector_type(8))) unsigned short ushort8;

__device__ __forceinline__ unsigned short f2bf(float x) {
  union { float f; unsigned u; } c; c.f = x;
  unsigned r = (c.u + 0x7fffu + ((c.u >> 16) & 1u)) >> 16;
  return (unsigned short)r;
}

__device__ __forceinline__ void gload_lds16(const void* g, void* l) {
  __builtin_amdgcn_global_load_lds(
      (const __attribute__((address_space(1))) unsigned int*)g,
      (__attribute__((address_space(3))) unsigned int*)l, 16, 0, 0);
}

// W [K][N] f32  ->  Wt [N][K] bf16
__global__ void wt_bf16_kernel(const float* __restrict__ W,
                               unsigned short* __restrict__ Wt,
                               int K, int N) {
  __shared__ float tile[32][33];
  int bx = blockIdx.x * 32;  // N dim
  int by = blockIdx.y * 32;  // K dim
  int tx = threadIdx.x & 31, ty = threadIdx.x >> 5;
  #pragma unroll
  for (int i = ty; i < 32; i += 8)
    tile[i][tx] = W[(size_t)(by + i) * N + bx + tx];
  __syncthreads();
  #pragma unroll
  for (int i = ty; i < 32; i += 8)
    Wt[(size_t)(bx + i) * K + by + tx] = f2bf(tile[tx][i]);
}

// Build X = bf16(concat(a, masked_mean(b[idx]))) ; one wave per row.
__global__ void build_x_kernel(const float* __restrict__ Aemb,
                               const float* __restrict__ Bemb,
                               const int* __restrict__ midx,
                               unsigned short* __restrict__ X,
                               int* __restrict__ counts) {
  int row = blockIdx.x * 4 + (threadIdx.x >> 6);
  int l = threadIdx.x & 63;
  float acc[8] = {0,0,0,0,0,0,0,0};
  int cnt = 0;
  const int* ip = midx + row * MM;
  #pragma unroll
  for (int m = 0; m < MM; ++m) {
    int id = ip[m];
    if (id >= 0) {
      ++cnt;
      const f32x4* p = (const f32x4*)(Bemb + (size_t)id * DM) + l * 2;
      f32x4 u = p[0], v = p[1];
      acc[0]+=u[0]; acc[1]+=u[1]; acc[2]+=u[2]; acc[3]+=u[3];
      acc[4]+=v[0]; acc[5]+=v[1]; acc[6]+=v[2]; acc[7]+=v[3];
    }
  }
  float inv = 1.0f / (float)(cnt > 0 ? cnt : 1);
  const f32x4* pa = (const f32x4*)(Aemb + (size_t)row * DM) + l * 2;
  f32x4 a0 = pa[0], a1 = pa[1];
  ushort8 va, vb;
  va[0]=f2bf(a0[0]); va[1]=f2bf(a0[1]); va[2]=f2bf(a0[2]); va[3]=f2bf(a0[3]);
  va[4]=f2bf(a1[0]); va[5]=f2bf(a1[1]); va[6]=f2bf(a1[2]); va[7]=f2bf(a1[3]);
  #pragma unroll
  for (int i = 0; i < 8; ++i) vb[i] = f2bf(acc[i] * inv);
  *(ushort8*)(X + (size_t)row * DI + l * 8) = va;
  *(ushort8*)(X + (size_t)row * DI + DM + l * 8) = vb;
  if (l == 0) counts[row] = cnt;
}

// C[M][N] = act(A[M][K]bf16 @ Bt[N][K]bf16^T + bias)  (m97 structure + T2 swizzle)
template<int RELU, int FINAL>
__global__ __launch_bounds__(256, 2)
void gemm_kernel(const unsigned short* __restrict__ A,
                 const unsigned short* __restrict__ Bt,
                 const float* __restrict__ bias,
                 unsigned short* __restrict__ Cb,
                 float* __restrict__ Cf,
                 const int* __restrict__ counts,
                 int M, int N, int K) {
  __shared__ __align__(16) unsigned short As[128 * 64];
  __shared__ __align__(16) unsigned short Bs[128 * 64];
  const int t = threadIdx.x;
  const int l = t & 63, w = t >> 6;
  const int wr = w >> 1, wc = w & 1;
  const int blockM = blockIdx.y * 128, blockN = blockIdx.x * 128;
  const unsigned short* Ab = A + (size_t)blockM * K;
  const unsigned short* Bb = Bt + (size_t)blockN * K;

  f32x4 acc[4][4];
  #pragma unroll
  for (int m = 0; m < 4; ++m)
    #pragma unroll
    for (int n = 0; n < 4; ++n) acc[m][n] = (f32x4){0.f, 0.f, 0.f, 0.f};

  // Staging: linear LDS dest (global_load_lds requirement), inverse-swizzled
  // global source column (rule #21: swizzle both sides or neither).
  int so_row[4], so_col[4];
  #pragma unroll
  for (int c = 0; c < 4; ++c) {
    int o = c * 4096 + t * 16;                 // linear byte offset in tile
    int row = o >> 7;                          // 128 B per row (64 bf16)
    int cb = (o & 127) ^ ((row & 7) << 4);     // swizzled source byte-in-row
    so_row[c] = row; so_col[c] = cb >> 1;
  }

  const int r = l & 15, ko = (l >> 4) * 8;
  const int swz = (r & 7) << 4;
  const char* Ac = (const char*)As;
  const char* Bc = (const char*)Bs;
  const int NT = K >> 6;

  // prologue stage k0 = 0
  #pragma unroll
  for (int c = 0; c < 4; ++c) {
    gload_lds16(Ab + (size_t)so_row[c] * K + so_col[c], (char*)As + c * 4096 + w * 1024);
    gload_lds16(Bb + (size_t)so_row[c] * K + so_col[c], (char*)Bs + c * 4096 + w * 1024);
  }

  for (int kt = 0; kt < NT; ++kt) {
    __syncthreads();   // compiler drains vmcnt before s_barrier -> tile ready
    #pragma unroll
    for (int kk = 0; kk < 64; kk += 32) {
      short8 aF[4], bF[4];
      #pragma unroll
      for (int m = 0; m < 4; ++m) {
        int byteo = ((wr * 64 + m * 16 + r) * 128 + (kk + ko) * 2) ^ swz;
        aF[m] = *(const short8*)(Ac + byteo);
      }
      #pragma unroll
      for (int n = 0; n < 4; ++n) {
        int byteo = ((wc * 64 + n * 16 + r) * 128 + (kk + ko) * 2) ^ swz;
        bF[n] = *(const short8*)(Bc + byteo);
      }
      #pragma unroll
      for (int m = 0; m < 4; ++m)
        #pragma unroll
        for (int n = 0; n < 4; ++n)
          acc[m][n] = __builtin_amdgcn_mfma_f32_16x16x32_bf16(aF[m], bF[n], acc[m][n], 0, 0, 0);
    }
    __syncthreads();   // all waves done reading before overwrite
    if (kt + 1 < NT) {
      int k0 = (kt + 1) << 6;
      #pragma unroll
      for (int c = 0; c < 4; ++c) {
        gload_lds16(Ab + (size_t)so_row[c] * K + k0 + so_col[c], (char*)As + c * 4096 + w * 1024);
        gload_lds16(Bb + (size_t)so_row[c] * K + k0 + so_col[c], (char*)Bs + c * 4096 + w * 1024);
      }
    }
  }

  // epilogue: C/D frag mapping col = lane&15, row = (lane>>4)*4 + reg
  float bn[4];
  #pragma unroll
  for (int n = 0; n < 4; ++n) bn[n] = bias[blockN + wc * 64 + n * 16 + r];
  const int rowBase = blockM + wr * 64 + (l >> 4) * 4;
  #pragma unroll
  for (int m = 0; m < 4; ++m) {
    #pragma unroll
    for (int j = 0; j < 4; ++j) {
      int grow = rowBase + m * 16 + j;
      if (FINAL) {
        float cm = (counts[grow] > 0) ? 1.0f : 0.0f;
        #pragma unroll
        for (int n = 0; n < 4; ++n) {
          float v = (acc[m][n][j] + bn[n]) * cm;
          Cf[(size_t)grow * N + blockN + wc * 64 + n * 16 + r] = v;
        }
      } else {
        #pragma unroll
        for (int n = 0; n < 4; ++n) {
          float v = acc[m][n][j] + bn[n];
          if (RELU) v = v > 0.f ? v : 0.f;
          Cb[(size_t)grow * N + blockN + wc * 64 + n * 16 + r] = f2bf(v);
        }
      }
    }
  }
}

extern "C" void kernel_launch(void* const* d_in, const int* in_sizes, int n_in,
                              void* d_out, int out_size, void* d_ws, size_t ws_size,
                              hipStream_t stream) {
  const float* a_emb = (const float*)d_in[0];
  const float* b_emb = (const float*)d_in[1];
  const int*   midx  = (const int*)d_in[2];
  const float* W_in  = (const float*)d_in[3];
  const float* b_in  = (const float*)d_in[4];
  const float* W_h   = (const float*)d_in[5];
  const float* b_h   = (const float*)d_in[6];
  const float* W_out = (const float*)d_in[7];
  const float* b_out = (const float*)d_in[8];

  char* ws = (char*)d_ws;
  unsigned short* X      = (unsigned short*)(ws);                          // 16 MiB (reused as H2)
  unsigned short* H1     = (unsigned short*)(ws + 16777216);               // 16 MiB
  unsigned short* Wt_in  = (unsigned short*)(ws + 33554432);               // 2 MiB
  unsigned short* Wt_h   = (unsigned short*)(ws + 35651584);               // 2 MiB
  unsigned short* Wt_out = (unsigned short*)(ws + 37748736);               // 1 MiB
  int*            counts = (int*)(ws + 38797312);                          // 32 KiB

  wt_bf16_kernel<<<dim3(32, 32), 256, 0, stream>>>(W_in,  Wt_in,  1024, 1024);
  wt_bf16_kernel<<<dim3(32, 32), 256, 0, stream>>>(W_h,   Wt_h,   1024, 1024);
  wt_bf16_kernel<<<dim3(16, 32), 256, 0, stream>>>(W_out, Wt_out, 1024, 512);
  build_x_kernel<<<2048, 256, 0, stream>>>(a_emb, b_emb, midx, X, counts);

  gemm_kernel<1, 0><<<dim3(8, 64), 256, 0, stream>>>(X,  Wt_in,  b_in,  H1, nullptr, nullptr, 8192, 1024, 1024);
  gemm_kernel<1, 0><<<dim3(8, 64), 256, 0, stream>>>(H1, Wt_h,   b_h,   X,  nullptr, nullptr, 8192, 1024, 1024);
  gemm_kernel<0, 1><<<dim3(4, 64), 256, 0, stream>>>(X,  Wt_out, b_out, nullptr, (float*)d_out, counts, 8192, 512, 1024);
}

// Round 2
// 114.474 us; speedup vs baseline: 1.1310x; 1.1310x over previous
//
#include <hip/hip_runtime.h>

#define DM 512
#define DI 1024
#define MM 16

typedef __attribute__((ext_vector_type(4))) float f32x4;
typedef __attribute__((ext_vector_type(8))) short short8;
typedef __attribute__((ext_vector_type(8))) unsigned short ushort8;

__device__ __forceinline__ unsigned short f2bf(float x) {
  union { float f; unsigned u; } c; c.f = x;
  unsigned r = (c.u + 0x7fffu + ((c.u >> 16) & 1u)) >> 16;
  return (unsigned short)r;
}

__device__ __forceinline__ void gload_lds16(const void* g, void* l) {
  __builtin_amdgcn_global_load_lds(
      (const __attribute__((address_space(1))) unsigned int*)g,
      (__attribute__((address_space(3))) unsigned int*)l, 16, 0, 0);
}

// ---- fused preprocessing: 3 weight transposes (f32 [K][N] -> bf16 [N][K])
// ---- + build_x, partitioned by blockIdx.x ranges. One launch total.

__device__ __forceinline__ void wt_tile(const float* __restrict__ W,
                                        unsigned short* __restrict__ Wt,
                                        int K, int N, int bx, int by,
                                        float (*tile)[33], int tx, int ty) {
  #pragma unroll
  for (int i = ty; i < 32; i += 8)
    tile[i][tx] = W[(size_t)(by + i) * N + bx + tx];
  __syncthreads();
  #pragma unroll
  for (int i = ty; i < 32; i += 8)
    Wt[(size_t)(bx + i) * K + by + tx] = f2bf(tile[tx][i]);
}

__global__ __launch_bounds__(256)
void prep_kernel(const float* __restrict__ Aemb,
                 const float* __restrict__ Bemb,
                 const int* __restrict__ midx,
                 const float* __restrict__ W_in,
                 const float* __restrict__ W_h,
                 const float* __restrict__ W_out,
                 unsigned short* __restrict__ X,
                 int* __restrict__ counts,
                 unsigned short* __restrict__ Wt_in,
                 unsigned short* __restrict__ Wt_h,
                 unsigned short* __restrict__ Wt_out) {
  __shared__ float tile[32][33];
  const int b = blockIdx.x;
  const int tx = threadIdx.x & 31, ty = threadIdx.x >> 5;
  if (b < 1024) {            // W_in  1024x1024: 32x32 blocks
    wt_tile(W_in, Wt_in, 1024, 1024, (b & 31) * 32, (b >> 5) * 32, tile, tx, ty);
    return;
  } else if (b < 2048) {     // W_h   1024x1024
    int lb = b - 1024;
    wt_tile(W_h, Wt_h, 1024, 1024, (lb & 31) * 32, (lb >> 5) * 32, tile, tx, ty);
    return;
  } else if (b < 2560) {     // W_out 1024x512: 16 x-blocks, 32 y-blocks
    int lb = b - 2048;
    wt_tile(W_out, Wt_out, 1024, 512, (lb & 15) * 32, (lb >> 4) * 32, tile, tx, ty);
    return;
  }
  // ---- build_x: X = bf16(concat(a, masked_mean(b[idx]))); one wave per row
  int row = __builtin_amdgcn_readfirstlane((b - 2560) * 4 + (threadIdx.x >> 6));
  int l = threadIdx.x & 63;
  float acc[8] = {0,0,0,0,0,0,0,0};
  int cnt = 0;
  const int* ip = midx + row * MM;
  #pragma unroll
  for (int m = 0; m < MM; ++m) {
    int id = ip[m];
    if (id >= 0) {
      ++cnt;
      const f32x4* p = (const f32x4*)(Bemb + (size_t)id * DM) + l * 2;
      f32x4 u = p[0], v = p[1];
      acc[0]+=u[0]; acc[1]+=u[1]; acc[2]+=u[2]; acc[3]+=u[3];
      acc[4]+=v[0]; acc[5]+=v[1]; acc[6]+=v[2]; acc[7]+=v[3];
    }
  }
  float inv = 1.0f / (float)(cnt > 0 ? cnt : 1);
  const f32x4* pa = (const f32x4*)(Aemb + (size_t)row * DM) + l * 2;
  f32x4 a0 = pa[0], a1 = pa[1];
  ushort8 va, vb;
  va[0]=f2bf(a0[0]); va[1]=f2bf(a0[1]); va[2]=f2bf(a0[2]); va[3]=f2bf(a0[3]);
  va[4]=f2bf(a1[0]); va[5]=f2bf(a1[1]); va[6]=f2bf(a1[2]); va[7]=f2bf(a1[3]);
  #pragma unroll
  for (int i = 0; i < 8; ++i) vb[i] = f2bf(acc[i] * inv);
  *(ushort8*)(X + (size_t)row * DI + l * 8) = va;
  *(ushort8*)(X + (size_t)row * DI + DM + l * 8) = vb;
  if (l == 0) counts[row] = cnt;
}

// C[M][N] = act(A[M][K]bf16 @ Bt[N][K]bf16^T + bias)  (m97 structure + T2 swizzle
//  + T1 chunked XCD swizzle)
template<int RELU, int FINAL>
__global__ __launch_bounds__(256, 2)
void gemm_kernel(const unsigned short* __restrict__ A,
                 const unsigned short* __restrict__ Bt,
                 const float* __restrict__ bias,
                 unsigned short* __restrict__ Cb,
                 float* __restrict__ Cf,
                 const int* __restrict__ counts,
                 int M, int N, int K) {
  __shared__ __align__(16) unsigned short As[128 * 64];
  __shared__ __align__(16) unsigned short Bs[128 * 64];
  const int t = threadIdx.x;
  const int l = t & 63, w = t >> 6;
  const int wr = w >> 1, wc = w & 1;

  // T1: chunked XCD swizzle (nwg % 8 == 0 for all our grids -> bijective).
  // Consecutive swizzled ids (same A-panel) land on the same XCD; each XCD's
  // working set = 8 A-panels (2 MB) + full B (<=2 MB) ~= its 4 MB L2.
  const int nwg = gridDim.x * gridDim.y;
  const int wg = blockIdx.y * gridDim.x + blockIdx.x;
  const int swzid = (wg & 7) * (nwg >> 3) + (wg >> 3);
  const int bx = swzid % gridDim.x, by = swzid / gridDim.x;

  const int blockM = by * 128, blockN = bx * 128;
  const unsigned short* Ab = A + (size_t)blockM * K;
  const unsigned short* Bb = Bt + (size_t)blockN * K;

  f32x4 acc[4][4];
  #pragma unroll
  for (int m = 0; m < 4; ++m)
    #pragma unroll
    for (int n = 0; n < 4; ++n) acc[m][n] = (f32x4){0.f, 0.f, 0.f, 0.f};

  // Staging: linear LDS dest (global_load_lds requirement), inverse-swizzled
  // global source column (rule #21: swizzle both sides or neither).
  int so_row[4], so_col[4];
  #pragma unroll
  for (int c = 0; c < 4; ++c) {
    int o = c * 4096 + t * 16;                 // linear byte offset in tile
    int row = o >> 7;                          // 128 B per row (64 bf16)
    int cb = (o & 127) ^ ((row & 7) << 4);     // swizzled source byte-in-row
    so_row[c] = row; so_col[c] = cb >> 1;
  }

  const int r = l & 15, ko = (l >> 4) * 8;
  const int swz = (r & 7) << 4;
  const char* Ac = (const char*)As;
  const char* Bc = (const char*)Bs;
  const int NT = K >> 6;

  // prologue stage k0 = 0
  #pragma unroll
  for (int c = 0; c < 4; ++c) {
    gload_lds16(Ab + (size_t)so_row[c] * K + so_col[c], (char*)As + c * 4096 + w * 1024);
    gload_lds16(Bb + (size_t)so_row[c] * K + so_col[c], (char*)Bs + c * 4096 + w * 1024);
  }

  for (int kt = 0; kt < NT; ++kt) {
    __syncthreads();   // compiler drains vmcnt before s_barrier -> tile ready
    #pragma unroll
    for (int kk = 0; kk < 64; kk += 32) {
      short8 aF[4], bF[4];
      #pragma unroll
      for (int m = 0; m < 4; ++m) {
        int byteo = ((wr * 64 + m * 16 + r) * 128 + (kk + ko) * 2) ^ swz;
        aF[m] = *(const short8*)(Ac + byteo);
      }
      #pragma unroll
      for (int n = 0; n < 4; ++n) {
        int byteo = ((wc * 64 + n * 16 + r) * 128 + (kk + ko) * 2) ^ swz;
        bF[n] = *(const short8*)(Bc + byteo);
      }
      #pragma unroll
      for (int m = 0; m < 4; ++m)
        #pragma unroll
        for (int n = 0; n < 4; ++n)
          acc[m][n] = __builtin_amdgcn_mfma_f32_16x16x32_bf16(aF[m], bF[n], acc[m][n], 0, 0, 0);
    }
    __syncthreads();   // all waves done reading before overwrite
    if (kt + 1 < NT) {
      int k0 = (kt + 1) << 6;
      #pragma unroll
      for (int c = 0; c < 4; ++c) {
        gload_lds16(Ab + (size_t)so_row[c] * K + k0 + so_col[c], (char*)As + c * 4096 + w * 1024);
        gload_lds16(Bb + (size_t)so_row[c] * K + k0 + so_col[c], (char*)Bs + c * 4096 + w * 1024);
      }
    }
  }

  // epilogue: C/D frag mapping col = lane&15, row = (lane>>4)*4 + reg
  float bn[4];
  #pragma unroll
  for (int n = 0; n < 4; ++n) bn[n] = bias[blockN + wc * 64 + n * 16 + r];
  const int rowBase = blockM + wr * 64 + (l >> 4) * 4;
  #pragma unroll
  for (int m = 0; m < 4; ++m) {
    #pragma unroll
    for (int j = 0; j < 4; ++j) {
      int grow = rowBase + m * 16 + j;
      if (FINAL) {
        float cm = (counts[grow] > 0) ? 1.0f : 0.0f;
        #pragma unroll
        for (int n = 0; n < 4; ++n) {
          float v = (acc[m][n][j] + bn[n]) * cm;
          Cf[(size_t)grow * N + blockN + wc * 64 + n * 16 + r] = v;
        }
      } else {
        #pragma unroll
        for (int n = 0; n < 4; ++n) {
          float v = acc[m][n][j] + bn[n];
          if (RELU) v = v > 0.f ? v : 0.f;
          Cb[(size_t)grow * N + blockN + wc * 64 + n * 16 + r] = f2bf(v);
        }
      }
    }
  }
}

extern "C" void kernel_launch(void* const* d_in, const int* in_sizes, int n_in,
                              void* d_out, int out_size, void* d_ws, size_t ws_size,
                              hipStream_t stream) {
  const float* a_emb = (const float*)d_in[0];
  const float* b_emb = (const float*)d_in[1];
  const int*   midx  = (const int*)d_in[2];
  const float* W_in  = (const float*)d_in[3];
  const float* b_in  = (const float*)d_in[4];
  const float* W_h   = (const float*)d_in[5];
  const float* b_h   = (const float*)d_in[6];
  const float* W_out = (const float*)d_in[7];
  const float* b_out = (const float*)d_in[8];

  char* ws = (char*)d_ws;
  unsigned short* X      = (unsigned short*)(ws);                          // 16 MiB (reused as H2)
  unsigned short* H1     = (unsigned short*)(ws + 16777216);               // 16 MiB
  unsigned short* Wt_in  = (unsigned short*)(ws + 33554432);               // 2 MiB
  unsigned short* Wt_h   = (unsigned short*)(ws + 35651584);               // 2 MiB
  unsigned short* Wt_out = (unsigned short*)(ws + 37748736);               // 1 MiB
  int*            counts = (int*)(ws + 38797312);                          // 32 KiB

  prep_kernel<<<4608, 256, 0, stream>>>(a_emb, b_emb, midx, W_in, W_h, W_out,
                                        X, counts, Wt_in, Wt_h, Wt_out);

  gemm_kernel<1, 0><<<dim3(8, 64), 256, 0, stream>>>(X,  Wt_in,  b_in,  H1, nullptr, nullptr, 8192, 1024, 1024);
  gemm_kernel<1, 0><<<dim3(8, 64), 256, 0, stream>>>(H1, Wt_h,   b_h,   X,  nullptr, nullptr, 8192, 1024, 1024);
  gemm_kernel<0, 1><<<dim3(4, 64), 256, 0, stream>>>(X,  Wt_out, b_out, nullptr, (float*)d_out, counts, 8192, 512, 1024);
}